// Round 1
// baseline (751.252 us; speedup 1.0000x reference)
//
#include <hip/hip_runtime.h>

// Fused: reshape -> (x @ w2) -> roll(H,+1) -> 7-tap H-conv (zero pad 3) with w1 -> roll(W,+1)
//
// out[b, c*12+i, h, (w+1)%112] = sum_{k=0..6} sum_{j=0..8} padded[b,c,h+k,w,j] * w1[i,k,j]
//   padded[p] = t4r[p-3] for 3<=p<=114 else 0
//   t4r[hh]   = t4[(hh-1) mod 112]            (roll along H)
//   t4[ht,j]  = sum_{ch=0..11} x[b, c*12+ch, ht, w] * w2[ch, j]
//
// => padded row p (valid) reads x row ht = (p-4) mod 112.
//
// Thread = one (b, c, w) column over a 28-row h-chunk; rolling 7x9 register
// window of t4 rows; weights staged in LDS (wave-uniform broadcast reads).

#define CHK 28   // h rows per thread
#define NCHK 4   // 112 / CHK

__global__ __launch_bounds__(128, 2)
void fused_shift_conv_kernel(const float* __restrict__ x,
                             const float* __restrict__ w1,   // (12,7,9)  [i][k][j]
                             const float* __restrict__ w2,   // (12,9)    [ch][j]
                             float* __restrict__ out)
{
    __shared__ float w1L[756];   // [(k*9+j)*12 + i]
    __shared__ float w2L[108];   // [j*12 + ch]

    // stage weights (transposed for i/ch-contiguous reads)
    for (int idx = threadIdx.x; idx < 756; idx += 128) {
        int i  = idx / 63;
        int kj = idx - i * 63;          // k*9 + j
        w1L[kj * 12 + i] = w1[idx];
    }
    for (int idx = threadIdx.x; idx < 108; idx += 128) {
        int ch = idx / 9;
        int j  = idx - ch * 9;
        w2L[j * 12 + ch] = w2[idx];
    }
    __syncthreads();

    const int w = threadIdx.x;
    if (w >= 112) return;

    const int bid = blockIdx.x;
    const int hc  = bid & 3;
    const int c   = (bid >> 2) & 1;
    const int b   = bid >> 3;
    const int h0  = hc * CHK;

    const size_t slab = (size_t)(b * 24 + c * 12) * 12544;  // 12544 = 112*112
    const float* xcol = x + slab + w;
    const int wout = (w == 111) ? 0 : (w + 1);              // fold roll(W,+1) into store
    float* ocol = out + slab + wout;

    float win[7][9];   // padded rows h..h+6, slot k holds row h+k

    // ---- prologue: fill padded rows p = h0 .. h0+6 ----
    #pragma unroll
    for (int t = 0; t < 7; ++t) {
        int p = h0 + t;
        if (p < 3) {                        // zero pad (only when h0 == 0)
            #pragma unroll
            for (int j = 0; j < 9; ++j) win[t][j] = 0.f;
        } else {
            int ht = p - 4;                 // (p-4) mod 112
            if (ht < 0) ht += 112;          // only p==3 wraps (ht=111)
            float xv[12];
            #pragma unroll
            for (int ch = 0; ch < 12; ++ch)
                xv[ch] = xcol[(size_t)ch * 12544 + (size_t)ht * 112];
            #pragma unroll
            for (int j = 0; j < 9; ++j) {
                float s = 0.f;
                #pragma unroll
                for (int ch = 0; ch < 12; ++ch)
                    s = fmaf(xv[ch], w2L[j * 12 + ch], s);
                win[t][j] = s;
            }
        }
    }

    // ---- main loop over output rows ----
    for (int h = h0; h < h0 + CHK; ++h) {
        float acc[12];
        #pragma unroll
        for (int i = 0; i < 12; ++i) acc[i] = 0.f;

        #pragma unroll
        for (int k = 0; k < 7; ++k) {
            #pragma unroll
            for (int j = 0; j < 9; ++j) {
                float p = win[k][j];
                const float* wl = &w1L[(k * 9 + j) * 12];
                #pragma unroll
                for (int i = 0; i < 12; ++i)
                    acc[i] = fmaf(p, wl[i], acc[i]);
            }
        }

        #pragma unroll
        for (int i = 0; i < 12; ++i)
            ocol[(size_t)i * 12544 + (size_t)h * 112] = acc[i];

        // shift window left
        #pragma unroll
        for (int k = 0; k < 6; ++k)
            #pragma unroll
            for (int j = 0; j < 9; ++j) win[k][j] = win[k + 1][j];

        // load padded row h+7 into slot 6
        int pn = h + 7;
        if (pn <= 114) {
            int ht = pn - 4;                // = h+3, in [3,110]: never wraps here
            float xv[12];
            #pragma unroll
            for (int ch = 0; ch < 12; ++ch)
                xv[ch] = xcol[(size_t)ch * 12544 + (size_t)ht * 112];
            #pragma unroll
            for (int j = 0; j < 9; ++j) {
                float s = 0.f;
                #pragma unroll
                for (int ch = 0; ch < 12; ++ch)
                    s = fmaf(xv[ch], w2L[j * 12 + ch], s);
                win[6][j] = s;
            }
        } else {
            #pragma unroll
            for (int j = 0; j < 9; ++j) win[6][j] = 0.f;
        }
    }
}

extern "C" void kernel_launch(void* const* d_in, const int* in_sizes, int n_in,
                              void* d_out, int out_size, void* d_ws, size_t ws_size,
                              hipStream_t stream) {
    (void)in_sizes; (void)n_in; (void)out_size; (void)d_ws; (void)ws_size;
    const float* x  = (const float*)d_in[0];
    const float* w1 = (const float*)d_in[1];
    const float* w2 = (const float*)d_in[2];
    float* out = (float*)d_out;

    dim3 grid(128 * 2 * NCHK);   // b * c * h-chunks = 1024 blocks
    dim3 block(128);             // lanes 0..111 = w
    fused_shift_conv_kernel<<<grid, block, 0, stream>>>(x, w1, w2, out);
}